// Round 4
// baseline (80.964 us; speedup 1.0000x reference)
//
#include <hip/hip_runtime.h>
#include <hip/hip_bf16.h>

typedef __attribute__((ext_vector_type(8))) short short8;
typedef __attribute__((ext_vector_type(4))) float f32x4;

#define NROW 16   // rows per block

// bf16 truncation (round-toward-zero). Safe here: the MLP result s = ||z3||^2
// cancels exactly in out = s*d / max(s*sqrt(n1*n2), eps); only d,n1,n2 (pure
// f32 from raw X) reach the output, so MLP rounding is irrelevant.
__device__ __forceinline__ unsigned int bfhi(float f) {
    return __builtin_bit_cast(unsigned int, f);
}
__device__ __forceinline__ unsigned int pack2(float lo, float hi) {
    return (bfhi(lo) >> 16) | (bfhi(hi) & 0xffff0000u);
}
__device__ __forceinline__ short8 pack_bf8(float4 a, float4 b) {
    uint4 u;
    u.x = pack2(a.x, a.y);
    u.y = pack2(a.z, a.w);
    u.z = pack2(b.x, b.y);
    u.w = pack2(b.z, b.w);
    return __builtin_bit_cast(short8, u);
}

// Byte-identical to the round-2 kernel (24.04 us anchor). This round is a
// DIAGNOSTIC: kernel_launch enqueues it 4x to measure the marginal cost of a
// warm launch and decompose dur_us into fixed overhead vs kernel time.
__global__ __launch_bounds__(512) void fused_qwn(
    const float* __restrict__ X,
    const float* __restrict__ W1, const float* __restrict__ b1,
    const float* __restrict__ W2, const float* __restrict__ b2,
    const float* __restrict__ W3, const float* __restrict__ b3,
    float* __restrict__ out)
{
    __shared__ __align__(16) unsigned short xq[NROW][776];     // 16x768 bf16, stride 776 (2-way max)
    __shared__ __align__(16) unsigned short z1_lds[NROW][136];
    __shared__ __align__(16) unsigned short z2_lds[NROW][72];
    __shared__ float s_lds[2][NROW];
    __shared__ float d_lds[NROW], n1_lds[NROW], n2_lds[NROW];

    const int tid  = threadIdx.x;
    const int wid  = tid >> 6;
    const int lane = tid & 63;
    const int l15  = lane & 15;
    const int l4   = lane >> 4;
    const int row0 = blockIdx.x * NROW;

    // ---------------- Phase 1: coalesced stream of X ----------------
    {
        const int r = tid >> 5;     // 0..15 (row)
        const int c = tid & 31;     // 0..31 (column slot)
        const float4* base = (const float4*)(X + (size_t)(row0 + r) * 2304);
        float dd = 0.f, aa = 0.f, bb = 0.f;
#pragma unroll
        for (int m = 0; m < 6; ++m) {
            const int j = c + 32 * m;          // float4 index in [0,192)
            float4 q  = base[j];               // Xq
            float4 p1 = base[192 + j];         // Xp1
            float4 p2 = base[384 + j];         // Xp2
            uint2 qb;
            qb.x = pack2(q.x, q.y);
            qb.y = pack2(q.z, q.w);
            *(uint2*)&xq[r][4 * j] = qb;
            dd += p1.x * p2.x + p1.y * p2.y + p1.z * p2.z + p1.w * p2.w;
            aa += p1.x * p1.x + p1.y * p1.y + p1.z * p1.z + p1.w * p1.w;
            bb += p2.x * p2.x + p2.y * p2.y + p2.z * p2.z + p2.w * p2.w;
        }
        // reduce across the 32 threads of this row (lane bits 0..4)
#pragma unroll
        for (int m = 1; m < 32; m <<= 1) {
            dd += __shfl_xor(dd, m);
            aa += __shfl_xor(aa, m);
            bb += __shfl_xor(bb, m);
        }
        if ((lane & 31) == 0) {
            d_lds[r]  = dd;
            n1_lds[r] = aa;
            n2_lds[r] = bb;
        }
    }
    __syncthreads();

    // ---------------- Phase 2: GEMM1 z1 = relu(Xq @ W1^T + b1) ----------------
    // 8 waves x 16 N-cols each. A from LDS, B from global f32 (L2-resident).
    {
        f32x4 acc = {0.f, 0.f, 0.f, 0.f};
        const float* bp = W1 + (size_t)(16 * wid + l15) * 768 + l4 * 8;
#pragma unroll 4
        for (int k0 = 0; k0 < 768; k0 += 32) {
            short8 a = *(const short8*)&xq[l15][k0 + l4 * 8];
            float4 w0 = *(const float4*)(bp + k0);
            float4 w1 = *(const float4*)(bp + k0 + 4);
            acc = __builtin_amdgcn_mfma_f32_16x16x32_bf16(a, pack_bf8(w0, w1), acc, 0, 0, 0);
        }
        float bb = b1[16 * wid + l15];
#pragma unroll
        for (int r = 0; r < 4; ++r) {
            float v = fmaxf(acc[r] + bb, 0.f);
            z1_lds[4 * l4 + r][16 * wid + l15] = (unsigned short)(bfhi(v) >> 16);
        }
    }
    __syncthreads();

    // ---------------- Phase 3: z2 = relu(z1 @ W2^T + b2), M=16,N=64,K=128 ----------------
    if (wid < 4) {
        f32x4 acc = {0.f, 0.f, 0.f, 0.f};
        const float* bp = W2 + (size_t)(16 * wid + l15) * 128 + l4 * 8;
#pragma unroll
        for (int ks = 0; ks < 4; ++ks) {
            short8 a = *(const short8*)&z1_lds[l15][ks * 32 + l4 * 8];
            float4 w0 = *(const float4*)(bp + ks * 32);
            float4 w1 = *(const float4*)(bp + ks * 32 + 4);
            acc = __builtin_amdgcn_mfma_f32_16x16x32_bf16(a, pack_bf8(w0, w1), acc, 0, 0, 0);
        }
        float bb = b2[16 * wid + l15];
#pragma unroll
        for (int r = 0; r < 4; ++r) {
            float v = fmaxf(acc[r] + bb, 0.f);
            z2_lds[4 * l4 + r][16 * wid + l15] = (unsigned short)(bfhi(v) >> 16);
        }
    }
    __syncthreads();

    // ---------------- Phase 4: z3 = relu(z2 @ W3^T + b3), M=16,N=32,K=64; s=||z3||^2 ----------------
    if (wid < 2) {
        f32x4 acc = {0.f, 0.f, 0.f, 0.f};
        const float* bp = W3 + (size_t)(16 * wid + l15) * 64 + l4 * 8;
#pragma unroll
        for (int ks = 0; ks < 2; ++ks) {
            short8 a = *(const short8*)&z2_lds[l15][ks * 32 + l4 * 8];
            float4 w0 = *(const float4*)(bp + ks * 32);
            float4 w1 = *(const float4*)(bp + ks * 32 + 4);
            acc = __builtin_amdgcn_mfma_f32_16x16x32_bf16(a, pack_bf8(w0, w1), acc, 0, 0, 0);
        }
        float bb = b3[16 * wid + l15];
        float sv[4];
#pragma unroll
        for (int r = 0; r < 4; ++r) {
            float v = fmaxf(acc[r] + bb, 0.f);
            sv[r] = v * v;
        }
#pragma unroll
        for (int m = 1; m < 16; m <<= 1) {
#pragma unroll
            for (int r = 0; r < 4; ++r) sv[r] += __shfl_xor(sv[r], m);
        }
        if (l15 == 0) {
#pragma unroll
            for (int r = 0; r < 4; ++r) s_lds[wid][4 * l4 + r] = sv[r];
        }
    }
    __syncthreads();

    // ---------------- Combine ----------------
    if (tid < NROW) {
        float s   = s_lds[0][tid] + s_lds[1][tid];
        float den = fmaxf(s * sqrtf(n1_lds[tid] * n2_lds[tid]), 1e-8f);
        out[row0 + tid] = (s * d_lds[tid]) / den;
    }
}

extern "C" void kernel_launch(void* const* d_in, const int* in_sizes, int n_in,
                              void* d_out, int out_size, void* d_ws, size_t ws_size,
                              hipStream_t stream)
{
    (void)in_sizes; (void)n_in; (void)out_size; (void)d_ws; (void)ws_size;
    const float* X  = (const float*)d_in[0];
    const float* W1 = (const float*)d_in[1];
    const float* b1 = (const float*)d_in[2];
    const float* W2 = (const float*)d_in[3];
    const float* b2 = (const float*)d_in[4];
    const float* W3 = (const float*)d_in[5];
    const float* b3 = (const float*)d_in[6];

    // DIAGNOSTIC: 4 idempotent launches. Marginal cost of launches 2-4
    // separates fixed overhead + cold-memory effects from true kernel time.
    fused_qwn<<<dim3(256), dim3(512), 0, stream>>>(X, W1, b1, W2, b2, W3, b3, (float*)d_out);
    fused_qwn<<<dim3(256), dim3(512), 0, stream>>>(X, W1, b1, W2, b2, W3, b3, (float*)d_out);
    fused_qwn<<<dim3(256), dim3(512), 0, stream>>>(X, W1, b1, W2, b2, W3, b3, (float*)d_out);
    fused_qwn<<<dim3(256), dim3(512), 0, stream>>>(X, W1, b1, W2, b2, W3, b3, (float*)d_out);
}

// Round 5
// 27.887 us; speedup vs baseline: 2.9033x; 2.9033x over previous
//
#include <hip/hip_runtime.h>
#include <hip/hip_bf16.h>

typedef __attribute__((ext_vector_type(8))) short short8;
typedef __attribute__((ext_vector_type(4))) float f32x4;

// bf16 truncation (round-toward-zero). Safe: s = ||z3||^2 cancels exactly in
// out = s*d / max(s*sqrt(n1*n2), eps); only d,n1,n2 (pure f32) reach out.
__device__ __forceinline__ unsigned int bfhi(float f) {
    return __builtin_bit_cast(unsigned int, f);
}
__device__ __forceinline__ unsigned int pack2(float lo, float hi) {
    return (bfhi(lo) >> 16) | (bfhi(hi) & 0xffff0000u);
}

// K0: convert W1 (128x768), W2 (64x128), W3 (32x64) f32 -> bf16 in ws.
// ushort layout: W1b @ 0 (98304), W2b @ 98304 (8192), W3b @ 106496 (2048).
__global__ __launch_bounds__(256) void cvt_weights(
    const float* __restrict__ W1, const float* __restrict__ W2,
    const float* __restrict__ W3, unsigned short* __restrict__ wsb)
{
    int i = blockIdx.x * 256 + threadIdx.x;
    if (i < 98304)        wsb[i] = (unsigned short)(bfhi(W1[i]) >> 16);
    else if (i < 106496)  wsb[i] = (unsigned short)(bfhi(W2[i - 98304]) >> 16);
    else if (i < 108544)  wsb[i] = (unsigned short)(bfhi(W3[i - 106496]) >> 16);
}

// K1: heterogeneous blocks. 576 blocks x 512 threads, <=128 VGPR, ~61 KB LDS
// -> 2 blocks/CU co-residency so P streaming overlaps Q's L2/MFMA work.
//   blocks 0..63   (Q): 64 rows each. Xq staged to LDS bf16 in 3 K-tiles of
//                       256; GEMM1 with each wave owning 16 unique W1b cols
//                       (196 KB bf16 L2-issue per block); z2, z3, s=||z3||^2.
//   blocks 64..575 (P): 8 rows each, wave w = row w: stream Xp1/Xp2, compute
//                       d, n1, n2 via full-wave butterfly reduce.
// Results to wsf: s @ 0, d @ 4096, n1 @ 8192, n2 @ 12288.
__global__ __launch_bounds__(512, 4) void pq_kernel(
    const float* __restrict__ X,
    const unsigned short* __restrict__ wsb,
    const float* __restrict__ b1,
    const float* __restrict__ b2,
    const float* __restrict__ b3,
    float* __restrict__ wsf)
{
    __shared__ __align__(16) unsigned short xq[64][264];  // 64x256 bf16 K-tile
    __shared__ __align__(16) unsigned short z1[64][136];  // 64x128 bf16
    __shared__ __align__(16) unsigned short z2[64][72];   // 64x64  bf16
    __shared__ float sred[2][64];

    const int tid  = threadIdx.x;
    const int wid  = tid >> 6;
    const int lane = tid & 63;
    const int l15  = lane & 15;
    const int l4   = lane >> 4;
    const int bid  = blockIdx.x;

    if (bid < 64) {
        // ================= Q path =================
        const int row0 = bid * 64;
        const unsigned short* W1b = wsb;
        const unsigned short* W2b = wsb + 98304;
        const unsigned short* W3b = wsb + 106496;

        // ---- GEMM1: z1 = relu(Xq @ W1^T + b1), M=64, N=128, K=768 ----
        // wave w: all 4 M-subtiles x its 16 unique cols [16w, 16w+16)
        f32x4 acc[4] = {{0,0,0,0},{0,0,0,0},{0,0,0,0},{0,0,0,0}};
        const unsigned short* bp = W1b + (size_t)(16 * wid + l15) * 768 + l4 * 8;
        for (int kt = 0; kt < 3; ++kt) {
            // stage 64 rows x 256 cols f32 -> bf16 LDS
#pragma unroll
            for (int m = 0; m < 8; ++m) {
                int i = tid + 512 * m;           // 0..4095
                int r = i >> 6, c4 = i & 63;     // row, float4-slot in tile
                float4 v = *(const float4*)(X + (size_t)(row0 + r) * 2304 + kt * 256 + c4 * 4);
                uint2 qb;
                qb.x = pack2(v.x, v.y);
                qb.y = pack2(v.z, v.w);
                *(uint2*)&xq[r][c4 * 4] = qb;
            }
            __syncthreads();
#pragma unroll
            for (int k0 = 0; k0 < 256; k0 += 32) {
                short8 b = *(const short8*)(bp + kt * 256 + k0);
#pragma unroll
                for (int m = 0; m < 4; ++m) {
                    short8 a = *(const short8*)&xq[16 * m + l15][k0 + l4 * 8];
                    acc[m] = __builtin_amdgcn_mfma_f32_16x16x32_bf16(a, b, acc[m], 0, 0, 0);
                }
            }
            __syncthreads();  // before next stage overwrites xq
        }
        {
            float bv = b1[16 * wid + l15];
#pragma unroll
            for (int m = 0; m < 4; ++m)
#pragma unroll
                for (int r = 0; r < 4; ++r) {
                    float v = fmaxf(acc[m][r] + bv, 0.f);
                    z1[16 * m + 4 * l4 + r][16 * wid + l15] = (unsigned short)(bfhi(v) >> 16);
                }
        }
        __syncthreads();

        // ---- GEMM2: z2 = relu(z1 @ W2^T + b2), M=64, N=64, K=128 ----
        // wave w: M-sub (w&3), N-half (w>>2) = 32 cols
        {
            const int ms = wid & 3, nh = wid >> 2;
            f32x4 a2[2] = {{0,0,0,0},{0,0,0,0}};
#pragma unroll
            for (int k0 = 0; k0 < 128; k0 += 32) {
                short8 a  = *(const short8*)&z1[16 * ms + l15][k0 + l4 * 8];
                short8 w0 = *(const short8*)(W2b + (size_t)(32 * nh + l15) * 128 + k0 + l4 * 8);
                short8 w1 = *(const short8*)(W2b + (size_t)(32 * nh + 16 + l15) * 128 + k0 + l4 * 8);
                a2[0] = __builtin_amdgcn_mfma_f32_16x16x32_bf16(a, w0, a2[0], 0, 0, 0);
                a2[1] = __builtin_amdgcn_mfma_f32_16x16x32_bf16(a, w1, a2[1], 0, 0, 0);
            }
            float bv0 = b2[32 * nh + l15], bv1 = b2[32 * nh + 16 + l15];
#pragma unroll
            for (int r = 0; r < 4; ++r) {
                float v0 = fmaxf(a2[0][r] + bv0, 0.f);
                float v1 = fmaxf(a2[1][r] + bv1, 0.f);
                z2[16 * ms + 4 * l4 + r][32 * nh + l15]      = (unsigned short)(bfhi(v0) >> 16);
                z2[16 * ms + 4 * l4 + r][32 * nh + 16 + l15] = (unsigned short)(bfhi(v1) >> 16);
            }
        }
        __syncthreads();

        // ---- GEMM3: z3 = relu(z2 @ W3^T + b3), M=64, N=32, K=64; s = ||z3||^2 ----
        // wave w: M-sub (w&3), N-group (w>>2) in {0,1}
        {
            const int ms = wid & 3, g = wid >> 2;
            f32x4 a3 = {0, 0, 0, 0};
#pragma unroll
            for (int k0 = 0; k0 < 64; k0 += 32) {
                short8 a = *(const short8*)&z2[16 * ms + l15][k0 + l4 * 8];
                short8 b = *(const short8*)(W3b + (size_t)(16 * g + l15) * 64 + k0 + l4 * 8);
                a3 = __builtin_amdgcn_mfma_f32_16x16x32_bf16(a, b, a3, 0, 0, 0);
            }
            float bv = b3[16 * g + l15];
            float sv[4];
#pragma unroll
            for (int r = 0; r < 4; ++r) {
                float v = fmaxf(a3[r] + bv, 0.f);
                sv[r] = v * v;
            }
#pragma unroll
            for (int m = 1; m < 16; m <<= 1)
#pragma unroll
                for (int r = 0; r < 4; ++r) sv[r] += __shfl_xor(sv[r], m);
            if (l15 == 0)
#pragma unroll
                for (int r = 0; r < 4; ++r) sred[g][16 * ms + 4 * l4 + r] = sv[r];
        }
        __syncthreads();
        if (tid < 64) wsf[row0 + tid] = sred[0][tid] + sred[1][tid];
    } else {
        // ================= P path =================
        const int row = (bid - 64) * 8 + wid;
        const float* base = X + (size_t)row * 2304;
        float4 p1[3], p2[3];
#pragma unroll
        for (int m = 0; m < 3; ++m) p1[m] = *(const float4*)(base + 768 + (lane + 64 * m) * 4);
#pragma unroll
        for (int m = 0; m < 3; ++m) p2[m] = *(const float4*)(base + 1536 + (lane + 64 * m) * 4);
        float dd = 0.f, aa = 0.f, bb = 0.f;
#pragma unroll
        for (int m = 0; m < 3; ++m) {
            float4 x = p1[m], y = p2[m];
            dd += x.x * y.x + x.y * y.y + x.z * y.z + x.w * y.w;
            aa += x.x * x.x + x.y * x.y + x.z * x.z + x.w * x.w;
            bb += y.x * y.x + y.y * y.y + y.z * y.z + y.w * y.w;
        }
#pragma unroll
        for (int m = 1; m < 64; m <<= 1) {
            dd += __shfl_xor(dd, m);
            aa += __shfl_xor(aa, m);
            bb += __shfl_xor(bb, m);
        }
        if (lane == 0) {
            wsf[4096 + row]  = dd;
            wsf[8192 + row]  = aa;
            wsf[12288 + row] = bb;
        }
    }
}

// K2: combine. out = s*d / max(s*sqrt(n1*n2), eps)
__global__ __launch_bounds__(512) void combine(
    const float* __restrict__ wsf, float* __restrict__ out)
{
    int i = blockIdx.x * 512 + threadIdx.x;
    float s  = wsf[i];
    float d  = wsf[4096 + i];
    float n1 = wsf[8192 + i];
    float n2 = wsf[12288 + i];
    out[i] = (s * d) / fmaxf(s * sqrtf(n1 * n2), 1e-8f);
}

extern "C" void kernel_launch(void* const* d_in, const int* in_sizes, int n_in,
                              void* d_out, int out_size, void* d_ws, size_t ws_size,
                              hipStream_t stream)
{
    (void)in_sizes; (void)n_in; (void)out_size; (void)ws_size;
    const float* X  = (const float*)d_in[0];
    const float* W1 = (const float*)d_in[1];
    const float* b1 = (const float*)d_in[2];
    const float* W2 = (const float*)d_in[3];
    const float* b2 = (const float*)d_in[4];
    const float* W3 = (const float*)d_in[5];
    const float* b3 = (const float*)d_in[6];

    float* wsf = (float*)d_ws;                              // s,d,n1,n2 : 4x4096 f32
    unsigned short* wsb = (unsigned short*)(wsf + 16384);   // bf16 weights

    cvt_weights<<<dim3(424), dim3(256), 0, stream>>>(W1, W2, W3, wsb);
    pq_kernel<<<dim3(576), dim3(512), 0, stream>>>(X, wsb, b1, b2, b3, wsf);
    combine<<<dim3(8), dim3(512), 0, stream>>>(wsf, (float*)d_out);
}